// Round 12
// baseline (349.614 us; speedup 1.0000x reference)
//
#include <hip/hip_runtime.h>
#include <math.h>

#define NBATCH 32
#define S      49152
#define NF     24          // frames (2048 samples each)
#define NB     16          // biquads
#define NBLK   4           // blocks per batch (R9 sweet spot)
#define CHUNK  16          // samples per thread
#define NCH    768         // threads per block
#define NWAVE  12          // waves per block
// 4 blocks per batch; block covers 768*16 = 12288 samples = 6 frames.

__device__ __forceinline__ float clampf(float x, float lo, float hi) {
    return fminf(fmaxf(x, lo), hi);
}

// 16 named scalar signal registers -- guaranteed SSA (no alloca; R1-R4 showed
// the allocator pins VGPR at 84 and spills float arrays regardless of hints).
#define FOREACH_S(OP) \
    OP(s00) OP(s01) OP(s02) OP(s03) OP(s04) OP(s05) OP(s06) OP(s07) \
    OP(s08) OP(s09) OP(s10) OP(s11) OP(s12) OP(s13) OP(s14) OP(s15)

#define DECL_S(x) float x;

// Phase A step: state only.  s' = T s + b*x
#define STEPA(x) { \
    const float n1_ = fmaf(t00, ic1, fmaf(t01, ic2, b0 * (x))); \
    const float n2_ = fmaf(t10, ic1, fmaf(t11, ic2, b1 * (x))); \
    ic1 = n1_; ic2 = n2_; }

// Phase C step: output + state.  y = c0*ic1 + c1*ic2 + c2*x, in place.
#define STEPC(x) { \
    const float y_  = fmaf(c0, ic1, fmaf(c1, ic2, c2 * (x))); \
    const float n1_ = fmaf(t00, ic1, fmaf(t01, ic2, b0 * (x))); \
    const float n2_ = fmaf(t10, ic1, fmaf(t11, ic2, b1 * (x))); \
    (x) = y_; ic1 = n1_; ic2 = n2_; }

// R11 post-mortem: cost scales with NBLK and has a big NBLK-independent
// floor -> back to R9 (NBLK=4, CHUNK=16). R12 attacks R9's remaining serial
// structure: ONE barrier per stage (was 2) and no wave0 bottleneck:
//  - lane63 writes wave aggregate to double-buffered LDS; single barrier;
//    EVERY wave redundantly scans the 12 aggregates and takes its own prefix
//    (no v-distribution round trip, no second barrier)
//  - every lane polls/folds predecessor slots itself via uniform-address
//    VMEM atomic loads (1 transaction/wave) -- a late publish stalls only
//    late waves, not the whole block behind a barrier
// Cross-block protocol unchanged (write-once slots, tag=f+1 != 0xAA poison;
// producers never wait -> no deadlock).
__global__ __launch_bounds__(NCH, 3)
void biquad_chain_kernel(const float* __restrict__ audio,
                         const float* __restrict__ params,
                         float* __restrict__ out,
                         unsigned int* __restrict__ ws)
{
    __shared__ float sc[NB][NF][16];     // stride 16 -> float4-aligned reads
    __shared__ float sgain[2][NF];       // [0]=in gain, [1]=out gain
    __shared__ float4 saggM[2][NWAVE];   // wave aggregate matrices (dbuf)
    __shared__ float  saggC[2][NWAVE][2];// wave aggregate constants (dbuf)

    const int t       = threadIdx.x;
    // XCD co-location swizzle (R8): all 4 quarters of a batch land on
    // blockIdx ≡ xcd (mod 8) -> same XCD, L2-local handshake.
    const int xcd     = blockIdx.x & 7;
    const int slot_   = blockIdx.x >> 3;
    const int bt      = xcd * 4 + (slot_ & 3);   // batch
    const int quarter = slot_ >> 2;              // which quarter of the signal
    const int lane    = t & 63;
    const int wave    = t >> 6;
    const int frame   = quarter * 6 + (wave >> 1);  // 2 waves per 2048-frame

    // ---------------- coefficient init (threads 0..383) ----------------
    if (t < NB * NF) {
        const int f  = t / NF;
        const int fr = t % NF;
        const float* P = params + (size_t)bt * 50 * NF;
        const float fn = P[(3 * f + 0) * NF + fr];
        const float gn = P[(3 * f + 1) * NF + fr];
        const float qn = P[(3 * f + 2) * NF + fr];

        float Q = __expf(-0.69314718f + qn * 3.4657359f);
        Q = clampf(Q, 0.1f, 100.0f);

        float lo, hi;
        int type;                        // 0 hp, 1 lp, 2 peak, 3 lowshelf, 4 highshelf
        if      (f == 0)  { lo = 20.0f;   hi = 500.0f;   type = 0; }
        else if (f == 15) { lo = 5000.0f; hi = 20000.0f; type = 1; }
        else if (f == 1)  { lo = 50.0f;   hi = 16000.0f; type = 3; }
        else if (f == 14) { lo = 50.0f;   hi = 16000.0f; type = 4; }
        else              { lo = 100.0f;  hi = 15000.0f; type = 2; }

        const float fc = __expf(__logf(lo) + fn * (__logf(hi) - __logf(lo)));
        float g_ = __tanf((float)M_PI * fc / 96000.0f);   // angle <= 0.655 rad
        g_ = clampf(g_, 1e-6f, 100.0f);
        const float gdb = -24.0f + 48.0f * gn;

        float a1, a2, a3, m0, m1, m2;
        if (type == 0 || type == 1) {
            const float k = 1.0f / Q;
            a1 = 1.0f / (1.0f + g_ * (g_ + k)); a2 = g_ * a1; a3 = g_ * a2;
            if (type == 0) { m0 = 1.0f; m1 = -k;   m2 = -1.0f; }
            else           { m0 = 0.0f; m1 = 0.0f; m2 = 1.0f;  }
        } else if (type == 2) {
            const float A = __expf(gdb * (2.30258509f / 40.0f));
            const float k = (gdb >= 0.0f) ? 1.0f / (Q * A) : A / Q;
            a1 = 1.0f / (1.0f + g_ * (g_ + k)); a2 = g_ * a1; a3 = g_ * a2;
            m0 = 1.0f; m1 = k * (A * A - 1.0f); m2 = 0.0f;
        } else {
            const float A  = __expf(gdb * (2.30258509f / 40.0f));
            const float sA = sqrtf(A);
            const float k  = 1.0f / Q;
            float gs;
            if (type == 3) gs = (gdb >= 0.0f) ? g_ / sA : g_ * sA;
            else           gs = (gdb >= 0.0f) ? g_ * sA : g_ / sA;
            a1 = 1.0f / (1.0f + gs * (gs + k)); a2 = gs * a1; a3 = gs * a2;
            if (type == 3) { m0 = 1.0f;  m1 = k * (A - 1.0f);      m2 = A * A - 1.0f; }
            else           { m0 = A * A; m1 = k * (1.0f - A) * A;  m2 = 1.0f - A * A; }
        }

        // affine per-sample form: s' = T s + b*x ; y = c0*ic1 + c1*ic2 + c2*x
        const float q2  = a2 * a2 + a3;
        const float t00 = 2.0f * a1 - 1.0f;
        const float t01 = -2.0f * a2;
        const float t10 = 2.0f * a1 * a2;
        const float t11 = 1.0f - 2.0f * q2;
        const float b0  = 2.0f * a2;
        const float b1  = 2.0f * q2;
        const float c0  = a1 * (m1 + m2 * a2);
        const float c1  = m2 * (1.0f - q2) - m1 * a2;
        const float c2  = m0 + m1 * a2 + m2 * q2;

        // M = T^16 by 4 squarings
        float u00 = t00, u01 = t01, u10 = t10, u11 = t11;
        #pragma unroll
        for (int i = 0; i < 4; i++) {
            const float n00 = u00 * u00 + u01 * u10;
            const float n01 = u00 * u01 + u01 * u11;
            const float n10 = u10 * u00 + u11 * u10;
            const float n11 = u10 * u01 + u11 * u11;
            u00 = n00; u01 = n01; u10 = n10; u11 = n11;
        }

        // layout: [0-3]=T [4-7]=b0,b1,c0,c1 [8-11]=c2,M00,M01,M10 [12]=M11
        sc[f][fr][0] = t00; sc[f][fr][1] = t01; sc[f][fr][2] = t10; sc[f][fr][3] = t11;
        sc[f][fr][4] = b0;  sc[f][fr][5] = b1;  sc[f][fr][6] = c0;  sc[f][fr][7] = c1;
        sc[f][fr][8] = c2;  sc[f][fr][9] = u00; sc[f][fr][10] = u01; sc[f][fr][11] = u10;
        sc[f][fr][12] = u11;
    }
    if (t >= 384 && t < 384 + 2 * NF) {
        const int idx = t - 384;
        const int which = idx / NF;
        const int fr    = idx % NF;
        const float* P = params + (size_t)bt * 50 * NF;
        const float p  = P[(48 + which) * NF + fr];
        const float db = -60.0f + 60.0f * p;
        sgain[which][fr] = __expf(db * (2.30258509f / 20.0f));
    }
    __syncthreads();

    // ---------------- load chunk (with input gain) ----------------
    FOREACH_S(DECL_S)
    {
        const float ing = sgain[0][frame];
        const float* base = audio + (size_t)bt * S
                          + (size_t)(quarter * NCH + t) * CHUNK;
        float4 q;
        q = *(const float4*)(base +  0); s00 = q.x*ing; s01 = q.y*ing; s02 = q.z*ing; s03 = q.w*ing;
        q = *(const float4*)(base +  4); s04 = q.x*ing; s05 = q.y*ing; s06 = q.z*ing; s07 = q.w*ing;
        q = *(const float4*)(base +  8); s08 = q.x*ing; s09 = q.y*ing; s10 = q.z*ing; s11 = q.w*ing;
        q = *(const float4*)(base + 12); s12 = q.x*ing; s13 = q.y*ing; s14 = q.z*ing; s15 = q.w*ing;
    }

    // ---------------- 16 cascaded stages ----------------
    #pragma unroll 1
    for (int f = 0; f < NB; f++) {
        const int buf = f & 1;
        const float4 q0 = *(const float4*)&sc[f][frame][0];  // t00 t01 t10 t11
        const float4 q1 = *(const float4*)&sc[f][frame][4];  // b0 b1 c0 c1
        const float4 q2 = *(const float4*)&sc[f][frame][8];  // c2 M00 M01 M10
        const float  M11v = sc[f][frame][12];
        const float t00 = q0.x, t01 = q0.y, t10 = q0.z, t11 = q0.w;
        const float b0  = q1.x, b1  = q1.y, c0  = q1.z, c1  = q1.w;
        const float c2  = q2.x;

        // Phase A: zero-state run over own chunk -> affine constant
        float ic1 = 0.0f, ic2 = 0.0f;
        FOREACH_S(STEPA)

        // constants-only Kogge-Stone: wave-uniform M=T^16 squared in place;
        // after the loop Md = M^64 (wave aggregate matrix).
        float Md00 = q2.y, Md01 = q2.z, Md10 = q2.w, Md11 = M11v;
        float Ac0 = ic1, Ac1 = ic2;
        #pragma unroll
        for (int d = 1; d < 64; d <<= 1) {
            const float lc0 = __shfl_up(Ac0, d);
            const float lc1 = __shfl_up(Ac1, d);
            if (lane >= d) {
                Ac0 = fmaf(Md00, lc0, fmaf(Md01, lc1, Ac0));
                Ac1 = fmaf(Md10, lc0, fmaf(Md11, lc1, Ac1));
            }
            const float n00 = Md00 * Md00 + Md01 * Md10;
            const float n01 = Md00 * Md01 + Md01 * Md11;
            const float n10 = Md10 * Md00 + Md11 * Md10;
            const float n11 = Md10 * Md01 + Md11 * Md11;
            Md00 = n00; Md01 = n01; Md10 = n10; Md11 = n11;
        }

        if (lane == 63) {
            saggM[buf][wave] = make_float4(Md00, Md01, Md10, Md11);
            saggC[buf][wave][0] = Ac0; saggC[buf][wave][1] = Ac1;
        }
        __syncthreads();   // the ONLY barrier this stage (dbuf makes it safe)

        // redundant second-level scan: every wave scans the 12 aggregates
        float G00 = 1.0f, G01 = 0.0f, G10 = 0.0f, G11 = 1.0f, Gc0 = 0.0f, Gc1 = 0.0f;
        if (lane < NWAVE) {
            const float4 m = saggM[buf][lane];
            G00 = m.x; G01 = m.y; G10 = m.z; G11 = m.w;
            Gc0 = saggC[buf][lane][0]; Gc1 = saggC[buf][lane][1];
        }
        #pragma unroll
        for (int d = 1; d < 16; d <<= 1) {
            const float l00 = __shfl_up(G00, d);
            const float l01 = __shfl_up(G01, d);
            const float l10 = __shfl_up(G10, d);
            const float l11 = __shfl_up(G11, d);
            const float lc0 = __shfl_up(Gc0, d);
            const float lc1 = __shfl_up(Gc1, d);
            if (lane >= d && lane < NWAVE) {
                const float n00 = G00 * l00 + G01 * l10;
                const float n01 = G00 * l01 + G01 * l11;
                const float n10 = G10 * l00 + G11 * l10;
                const float n11 = G10 * l01 + G11 * l11;
                const float nc0 = G00 * lc0 + G01 * lc1 + Gc0;
                const float nc1 = G10 * lc0 + G11 * lc1 + Gc1;
                G00 = n00; G01 = n01; G10 = n10; G11 = n11;
                Gc0 = nc0; Gc1 = nc1;
            }
        }

        const unsigned int tag = (unsigned int)(f + 1);
        unsigned int* stagebase = ws + ((bt * NB + f) * NBLK) * 8;

        // publish block aggregate (inclusive scan at lane 11) -- wave 0 only
        if (wave == 0 && quarter < NBLK - 1 && lane == NWAVE - 1) {
            unsigned int* slot = stagebase + quarter * 8;
            float* dp = (float*)(slot + 1);
            __hip_atomic_store(&dp[0], G00, __ATOMIC_RELAXED, __HIP_MEMORY_SCOPE_AGENT);
            __hip_atomic_store(&dp[1], G01, __ATOMIC_RELAXED, __HIP_MEMORY_SCOPE_AGENT);
            __hip_atomic_store(&dp[2], G10, __ATOMIC_RELAXED, __HIP_MEMORY_SCOPE_AGENT);
            __hip_atomic_store(&dp[3], G11, __ATOMIC_RELAXED, __HIP_MEMORY_SCOPE_AGENT);
            __hip_atomic_store(&dp[4], Gc0, __ATOMIC_RELAXED, __HIP_MEMORY_SCOPE_AGENT);
            __hip_atomic_store(&dp[5], Gc1, __ATOMIC_RELAXED, __HIP_MEMORY_SCOPE_AGENT);
            __hip_atomic_store(slot, tag, __ATOMIC_RELEASE, __HIP_MEMORY_SCOPE_AGENT);
        }

        // every wave polls/folds its predecessors itself (uniform-address
        // VMEM loads; <=3 predecessors; block-uniform loop count)
        float S0x = 0.0f, S0y = 0.0f;
        for (int k2 = 0; k2 < quarter; k2++) {
            unsigned int* slot = stagebase + k2 * 8;
            while (__hip_atomic_load(slot, __ATOMIC_ACQUIRE, __HIP_MEMORY_SCOPE_AGENT) != tag) {
                __builtin_amdgcn_s_sleep(1);
            }
            float* dp = (float*)(slot + 1);
            const float m00 = __hip_atomic_load(&dp[0], __ATOMIC_RELAXED, __HIP_MEMORY_SCOPE_AGENT);
            const float m01 = __hip_atomic_load(&dp[1], __ATOMIC_RELAXED, __HIP_MEMORY_SCOPE_AGENT);
            const float m10 = __hip_atomic_load(&dp[2], __ATOMIC_RELAXED, __HIP_MEMORY_SCOPE_AGENT);
            const float m11 = __hip_atomic_load(&dp[3], __ATOMIC_RELAXED, __HIP_MEMORY_SCOPE_AGENT);
            const float cc0 = __hip_atomic_load(&dp[4], __ATOMIC_RELAXED, __HIP_MEMORY_SCOPE_AGENT);
            const float cc1 = __hip_atomic_load(&dp[5], __ATOMIC_RELAXED, __HIP_MEMORY_SCOPE_AGENT);
            const float nx = m00 * S0x + m01 * S0y + cc0;
            const float ny = m10 * S0x + m11 * S0y + cc1;
            S0x = nx; S0y = ny;
        }

        // this wave's exclusive prefix = scan value at lane (wave-1)
        float Pm00 = 1.0f, Pm01 = 0.0f, Pm10 = 0.0f, Pm11 = 1.0f;
        float Pc0 = 0.0f, Pc1 = 0.0f;
        {
            const int wsrc = (wave > 0) ? (wave - 1) : 0;
            const float a = __shfl(G00, wsrc);
            const float b = __shfl(G01, wsrc);
            const float c = __shfl(G10, wsrc);
            const float dd = __shfl(G11, wsrc);
            const float e = __shfl(Gc0, wsrc);
            const float g2 = __shfl(Gc1, wsrc);
            if (wave > 0) { Pm00 = a; Pm01 = b; Pm10 = c; Pm11 = dd; Pc0 = e; Pc1 = g2; }
        }

        // v = wave incoming state
        const float vx = Pm00 * S0x + Pm01 * S0y + Pc0;
        const float vy = Pm10 * S0x + Pm11 * S0y + Pc1;

        // lane-exclusive constants
        float ce0 = __shfl_up(Ac0, 1);
        float ce1 = __shfl_up(Ac1, 1);
        if (lane == 0) { ce0 = 0.0f; ce1 = 0.0f; }

        // w = M^lane * v via in-register binary exponentiation
        float w0 = vx, w1 = vy;
        float p00 = q2.y, p01 = q2.z, p10 = q2.w, p11 = M11v;
        #pragma unroll
        for (int b = 0; b < 6; b++) {
            if (lane & (1 << b)) {
                const float nw0 = fmaf(p00, w0, p01 * w1);
                const float nw1 = fmaf(p10, w0, p11 * w1);
                w0 = nw0; w1 = nw1;
            }
            if (b < 5) {
                const float n00 = p00 * p00 + p01 * p10;
                const float n01 = p00 * p01 + p01 * p11;
                const float n10 = p10 * p00 + p11 * p10;
                const float n11 = p10 * p01 + p11 * p11;
                p00 = n00; p01 = n01; p10 = n10; p11 = n11;
            }
        }
        ic1 = w0 + ce0;
        ic2 = w1 + ce1;

        // Phase C: true run from incoming state, write outputs in place
        FOREACH_S(STEPC)
    }

    // ---------------- store (with output gain) ----------------
    {
        const float og = sgain[1][frame];
        float* base = out + (size_t)bt * S + (size_t)(quarter * NCH + t) * CHUNK;
        float4 q;
        q.x = s00*og; q.y = s01*og; q.z = s02*og; q.w = s03*og; *(float4*)(base +  0) = q;
        q.x = s04*og; q.y = s05*og; q.z = s06*og; q.w = s07*og; *(float4*)(base +  4) = q;
        q.x = s08*og; q.y = s09*og; q.z = s10*og; q.w = s11*og; *(float4*)(base +  8) = q;
        q.x = s12*og; q.y = s13*og; q.z = s14*og; q.w = s15*og; *(float4*)(base + 12) = q;
    }
}

extern "C" void kernel_launch(void* const* d_in, const int* in_sizes, int n_in,
                              void* d_out, int out_size, void* d_ws, size_t ws_size,
                              hipStream_t stream)
{
    const float* audio  = (const float*)d_in[0];
    const float* params = (const float*)d_in[1];
    float* out = (float*)d_out;
    unsigned int* ws = (unsigned int*)d_ws;
    biquad_chain_kernel<<<NBLK * NBATCH, NCH, 0, stream>>>(audio, params, out, ws);
}

// Round 13
// 140.815 us; speedup vs baseline: 2.4828x; 2.4828x over previous
//
#include <hip/hip_runtime.h>
#include <math.h>

#define NBATCH 32
#define S      49152
#define NF     24          // frames
#define FRAME  2048
#define NB     16          // biquads
#define TPB    256         // threads per frame-block
#define FCHUNK 8           // samples per thread in frame_pass

// ws layout (floats): A[32][24][1024] | b[32][24][32] | s[32][24][32]
#define WS_A_ELEMS (NBATCH * NF * 1024)
#define WS_B_ELEMS (NBATCH * NF * 32)
#define WS_S_ELEMS (NBATCH * NF * 32)

__device__ __forceinline__ float clampf(float x, float lo, float hi) {
    return fminf(fmaxf(x, lo), hi);
}

// ---- shared coefficient math: computes the 13-float per-(filter,frame) set
__device__ __forceinline__ void filter_coeffs(int f, float fn, float gn, float qn,
                                              float* dst /*13+ floats*/)
{
    float Q = __expf(-0.69314718f + qn * 3.4657359f);
    Q = clampf(Q, 0.1f, 100.0f);

    float lo, hi; int type;
    if      (f == 0)  { lo = 20.0f;   hi = 500.0f;   type = 0; }
    else if (f == 15) { lo = 5000.0f; hi = 20000.0f; type = 1; }
    else if (f == 1)  { lo = 50.0f;   hi = 16000.0f; type = 3; }
    else if (f == 14) { lo = 50.0f;   hi = 16000.0f; type = 4; }
    else              { lo = 100.0f;  hi = 15000.0f; type = 2; }

    const float fc = __expf(__logf(lo) + fn * (__logf(hi) - __logf(lo)));
    float g_ = __tanf((float)M_PI * fc / 96000.0f);   // angle <= 0.655 rad
    g_ = clampf(g_, 1e-6f, 100.0f);
    const float gdb = -24.0f + 48.0f * gn;

    float a1, a2, a3, m0, m1, m2;
    if (type == 0 || type == 1) {
        const float k = 1.0f / Q;
        a1 = 1.0f / (1.0f + g_ * (g_ + k)); a2 = g_ * a1; a3 = g_ * a2;
        if (type == 0) { m0 = 1.0f; m1 = -k;   m2 = -1.0f; }
        else           { m0 = 0.0f; m1 = 0.0f; m2 = 1.0f;  }
    } else if (type == 2) {
        const float A = __expf(gdb * (2.30258509f / 40.0f));
        const float k = (gdb >= 0.0f) ? 1.0f / (Q * A) : A / Q;
        a1 = 1.0f / (1.0f + g_ * (g_ + k)); a2 = g_ * a1; a3 = g_ * a2;
        m0 = 1.0f; m1 = k * (A * A - 1.0f); m2 = 0.0f;
    } else {
        const float A  = __expf(gdb * (2.30258509f / 40.0f));
        const float sA = sqrtf(A);
        const float k  = 1.0f / Q;
        float gs;
        if (type == 3) gs = (gdb >= 0.0f) ? g_ / sA : g_ * sA;
        else           gs = (gdb >= 0.0f) ? g_ * sA : g_ / sA;
        a1 = 1.0f / (1.0f + gs * (gs + k)); a2 = gs * a1; a3 = gs * a2;
        if (type == 3) { m0 = 1.0f;  m1 = k * (A - 1.0f);      m2 = A * A - 1.0f; }
        else           { m0 = A * A; m1 = k * (1.0f - A) * A;  m2 = 1.0f - A * A; }
    }

    const float q2 = a2 * a2 + a3;
    dst[0] = 2.0f * a1 - 1.0f;            // t00
    dst[1] = -2.0f * a2;                  // t01
    dst[2] = 2.0f * a1 * a2;              // t10
    dst[3] = 1.0f - 2.0f * q2;            // t11
    dst[4] = 2.0f * a2;                   // b0
    dst[5] = 2.0f * q2;                   // b1
    dst[6] = a1 * (m1 + m2 * a2);         // c0
    dst[7] = m2 * (1.0f - q2) - m1 * a2;  // c1
    dst[8] = m0 + m1 * a2 + m2 * q2;      // c2
    // M8 = T^8 (3 squarings)
    float u00 = dst[0], u01 = dst[1], u10 = dst[2], u11 = dst[3];
    #pragma unroll
    for (int i = 0; i < 3; i++) {
        const float n00 = u00*u00 + u01*u10;
        const float n01 = u00*u01 + u01*u11;
        const float n10 = u10*u00 + u11*u10;
        const float n11 = u10*u01 + u11*u11;
        u00=n00; u01=n01; u10=n10; u11=n11;
    }
    dst[9] = u00; dst[10] = u01; dst[11] = u10; dst[12] = u11;
}

// 8 named signal registers (SSA; alloca arrays spill per R1-R4)
#define FOREACH_S8(OP) \
    OP(s00) OP(s01) OP(s02) OP(s03) OP(s04) OP(s05) OP(s06) OP(s07)
#define DECL_S(x) float x;
#define STEPA(x) { \
    const float n1_ = fmaf(t00, ic1, fmaf(t01, ic2, b0 * (x))); \
    const float n2_ = fmaf(t10, ic1, fmaf(t11, ic2, b1 * (x))); \
    ic1 = n1_; ic2 = n2_; }
#define STEPC(x) { \
    const float y_  = fmaf(c0, ic1, fmaf(c1, ic2, c2 * (x))); \
    const float n1_ = fmaf(t00, ic1, fmaf(t01, ic2, b0 * (x))); \
    const float n2_ = fmaf(t10, ic1, fmaf(t11, ic2, b1 * (x))); \
    (x) = y_; ic1 = n1_; ic2 = n2_; }

// ---------------------------------------------------------------------------
// frame_pass: one block per (batch, frame). mode 0 = analyze (write A_f, b_f),
// mode 1 = apply (read s_in, write gained output). No inter-block deps at all.
// ---------------------------------------------------------------------------
__global__ __launch_bounds__(TPB)
void frame_pass(const float* __restrict__ audio,
                const float* __restrict__ params,
                float* __restrict__ out,
                float* __restrict__ wsA,
                float* __restrict__ wsB,
                const float* __restrict__ wsS,
                int mode)
{
    __shared__ float  sf[NB][16];       // per-filter coeffs (13 used)
    __shared__ float  sg[2];            // in/out gain for this frame
    __shared__ float  cAgg[2][4][2];    // wave constants, double-buffered
    __shared__ float  bfl[NB][2];       // zero-state final states (mode 0)
    __shared__ float  sinl[32];         // incoming cascade state (mode 1)
    __shared__ float4 Mtx[2][16][16];   // 32x32 as 2x2 blocks, ping-pong

    const int t    = threadIdx.x;
    const int blk  = blockIdx.x;
    const int bt   = blk / NF;
    const int fr   = blk % NF;
    const int lane = t & 63;
    const int wave = t >> 6;

    // ---- init: coeffs (t<16), gains (t=16,17), s_in (mode1, t=32..63)
    if (t < NB) {
        const float* P = params + (size_t)bt * 50 * NF;
        const float fn = P[(3 * t + 0) * NF + fr];
        const float gn = P[(3 * t + 1) * NF + fr];
        const float qn = P[(3 * t + 2) * NF + fr];
        filter_coeffs(t, fn, gn, qn, sf[t]);
    }
    if (t == 16 || t == 17) {
        const int which = t - 16;
        const float* P = params + (size_t)bt * 50 * NF;
        const float p  = P[(48 + which) * NF + fr];
        sg[which] = __expf((-60.0f + 60.0f * p) * (2.30258509f / 20.0f));
    }
    if (mode == 1 && t >= 32 && t < 64) {
        sinl[t - 32] = wsS[(size_t)(bt * NF + fr) * 32 + (t - 32)];
    }
    __syncthreads();

    // ---- load chunk (with input gain)
    FOREACH_S8(DECL_S)
    {
        const float ing = sg[0];
        const float* base = audio + (size_t)bt * S + (size_t)fr * FRAME
                          + (size_t)t * FCHUNK;
        float4 q;
        q = *(const float4*)(base + 0); s00 = q.x*ing; s01 = q.y*ing; s02 = q.z*ing; s03 = q.w*ing;
        q = *(const float4*)(base + 4); s04 = q.x*ing; s05 = q.y*ing; s06 = q.z*ing; s07 = q.w*ing;
    }

    // ---- 16 cascaded stages, in-block only (ONE barrier per stage)
    #pragma unroll 1
    for (int f = 0; f < NB; f++) {
        const int buf = f & 1;
        const float4 q0 = *(const float4*)&sf[f][0];  // T
        const float4 q1 = *(const float4*)&sf[f][4];  // b0 b1 c0 c1
        const float4 q2 = *(const float4*)&sf[f][8];  // c2 M8(00,01,10)
        const float  m811 = sf[f][12];
        const float t00 = q0.x, t01 = q0.y, t10 = q0.z, t11 = q0.w;
        const float b0  = q1.x, b1  = q1.y, c0  = q1.z, c1  = q1.w;
        const float c2  = q2.x;

        // Phase A (zero-state over own 8 samples)
        float ic1 = 0.0f, ic2 = 0.0f;
        FOREACH_S8(STEPA)

        // constants-only Kogge-Stone; M squared in place: ends at G = T^512
        float Md00 = q2.y, Md01 = q2.z, Md10 = q2.w, Md11 = m811;
        float Ac0 = ic1, Ac1 = ic2;
        #pragma unroll
        for (int d = 1; d < 64; d <<= 1) {
            const float lc0 = __shfl_up(Ac0, d);
            const float lc1 = __shfl_up(Ac1, d);
            if (lane >= d) {
                Ac0 = fmaf(Md00, lc0, fmaf(Md01, lc1, Ac0));
                Ac1 = fmaf(Md10, lc0, fmaf(Md11, lc1, Ac1));
            }
            const float n00 = Md00*Md00 + Md01*Md10;
            const float n01 = Md00*Md01 + Md01*Md11;
            const float n10 = Md10*Md00 + Md11*Md10;
            const float n11 = Md10*Md01 + Md11*Md11;
            Md00=n00; Md01=n01; Md10=n10; Md11=n11;
        }
        // Md = G = T^512 (wave-uniform; same for all 4 waves of this frame)

        if (lane == 63) { cAgg[buf][wave][0] = Ac0; cAgg[buf][wave][1] = Ac1; }
        __syncthreads();

        // wave incoming state: u = G^wave * s_in + sum G^(w-1-j) c_j
        float u0, u1;
        if (mode == 1) { u0 = sinl[2*f]; u1 = sinl[2*f+1]; }
        else           { u0 = 0.0f;      u1 = 0.0f;        }
        for (int j = 0; j < wave; j++) {
            const float cj0 = cAgg[buf][j][0];
            const float cj1 = cAgg[buf][j][1];
            const float n0 = fmaf(Md00, u0, fmaf(Md01, u1, cj0));
            const float n1 = fmaf(Md10, u0, fmaf(Md11, u1, cj1));
            u0 = n0; u1 = n1;
        }

        // mode 0: thread 0 records frame-final zero-state = b_f pair
        if (mode == 0 && t == 0) {
            float z0 = 0.0f, z1 = 0.0f;
            #pragma unroll
            for (int j = 0; j < 4; j++) {
                const float n0 = fmaf(Md00, z0, fmaf(Md01, z1, cAgg[buf][j][0]));
                const float n1 = fmaf(Md10, z0, fmaf(Md11, z1, cAgg[buf][j][1]));
                z0 = n0; z1 = n1;
            }
            bfl[f][0] = z0; bfl[f][1] = z1;
        }

        // lane-exclusive constants
        float ce0 = __shfl_up(Ac0, 1);
        float ce1 = __shfl_up(Ac1, 1);
        if (lane == 0) { ce0 = 0.0f; ce1 = 0.0f; }

        // w = M8^lane * u (binexp with in-register squaring)
        float w0 = u0, w1 = u1;
        float p00 = q2.y, p01 = q2.z, p10 = q2.w, p11 = m811;
        #pragma unroll
        for (int b = 0; b < 6; b++) {
            if (lane & (1 << b)) {
                const float n0 = fmaf(p00, w0, p01 * w1);
                const float n1 = fmaf(p10, w0, p11 * w1);
                w0 = n0; w1 = n1;
            }
            if (b < 5) {
                const float n00 = p00*p00 + p01*p10;
                const float n01 = p00*p01 + p01*p11;
                const float n10 = p10*p00 + p11*p10;
                const float n11 = p10*p01 + p11*p11;
                p00=n00; p01=n01; p10=n10; p11=n11;
            }
        }
        ic1 = w0 + ce0;
        ic2 = w1 + ce1;

        // Phase C in place
        FOREACH_S8(STEPC)
    }
    __syncthreads();

    if (mode == 1) {
        const float og = sg[1];
        float* base = out + (size_t)bt * S + (size_t)fr * FRAME + (size_t)t * FCHUNK;
        float4 q;
        q.x = s00*og; q.y = s01*og; q.z = s02*og; q.w = s03*og; *(float4*)(base + 0) = q;
        q.x = s04*og; q.y = s05*og; q.z = s06*og; q.w = s07*og; *(float4*)(base + 4) = q;
        return;
    }

    // ---- mode 0: write b_f; build + square the 32x32 cascade matrix
    if (t < 32) wsB[(size_t)(bt * NF + fr) * 32 + t] = bfl[t >> 1][t & 1];

    if (fr < NF - 1) {     // A of the last frame is never used by the relay
        // map tid -> lower-triangular 2x2 block (i,j), 136 blocks
        int ii = -1, jj = 0;
        if (t < 136) {
            int rem = t;
            for (int r = 0; r < 16; r++) {
                if (rem < r + 1) { ii = r; jj = rem; break; }
                rem -= r + 1;
            }
        }
        if (ii >= 0) {
            float4 blkv;
            if (ii == jj) {
                blkv = make_float4(sf[ii][0], sf[ii][1], sf[ii][2], sf[ii][3]);
            } else {
                float pc2 = 1.0f;
                for (int k = jj + 1; k < ii; k++) pc2 *= sf[k][8];
                const float w0 = pc2 * sf[jj][6];
                const float w1 = pc2 * sf[jj][7];
                blkv = make_float4(sf[ii][4]*w0, sf[ii][4]*w1, sf[ii][5]*w0, sf[ii][5]*w1);
            }
            Mtx[0][ii][jj] = blkv;
        }
        __syncthreads();

        // 11 squarings: M^2048 (block-triangular: k ranges j..i only)
        #pragma unroll 1
        for (int it = 0; it < 11; it++) {
            const int rb = it & 1;
            if (ii >= 0) {
                float a00 = 0.0f, a01 = 0.0f, a10 = 0.0f, a11 = 0.0f;
                for (int k = jj; k <= ii; k++) {
                    const float4 L = Mtx[rb][ii][k];
                    const float4 R = Mtx[rb][k][jj];
                    a00 += L.x*R.x + L.y*R.z;
                    a01 += L.x*R.y + L.y*R.w;
                    a10 += L.z*R.x + L.w*R.z;
                    a11 += L.z*R.y + L.w*R.w;
                }
                Mtx[rb ^ 1][ii][jj] = make_float4(a00, a01, a10, a11);
            }
            __syncthreads();
        }

        // write A_f row-major 32x32 (4 elements per thread)
        float* Aout = wsA + (size_t)(bt * NF + fr) * 1024;
        #pragma unroll
        for (int e = 0; e < 4; e++) {
            const int idx = t * 4 + e;
            const int r = idx >> 5, c = idx & 31;
            float v = 0.0f;
            if ((r >> 1) >= (c >> 1)) {
                const float4 bb = Mtx[1][r >> 1][c >> 1];
                v = (r & 1) ? ((c & 1) ? bb.w : bb.z) : ((c & 1) ? bb.y : bb.x);
            }
            Aout[idx] = v;
        }
    }
}

// ---------------------------------------------------------------------------
// relay: per batch, serial over 24 frames: s <- A_k s + b_k; store s_in(k).
// ---------------------------------------------------------------------------
__global__ __launch_bounds__(64)
void relay_kernel(const float* __restrict__ wsA,
                  const float* __restrict__ wsB,
                  float* __restrict__ wsS)
{
    const int bt = blockIdx.x;
    const int l  = threadIdx.x;
    const int lr = l & 31;            // lanes 32..63 shadow rows 0..31 (unused)

    float s = 0.0f;                   // lane lr holds state element lr
    #pragma unroll 1
    for (int k = 0; k < NF; k++) {
        if (l < 32) wsS[(size_t)(bt * NF + k) * 32 + l] = s;
        if (k == NF - 1) break;
        const float* Ar = wsA + (size_t)(bt * NF + k) * 1024 + lr * 32;
        const float4 r0 = *(const float4*)(Ar +  0);
        const float4 r1 = *(const float4*)(Ar +  4);
        const float4 r2 = *(const float4*)(Ar +  8);
        const float4 r3 = *(const float4*)(Ar + 12);
        const float4 r4 = *(const float4*)(Ar + 16);
        const float4 r5 = *(const float4*)(Ar + 20);
        const float4 r6 = *(const float4*)(Ar + 24);
        const float4 r7 = *(const float4*)(Ar + 28);
        float acc = wsB[(size_t)(bt * NF + k) * 32 + lr];
        acc += r0.x*__shfl(s, 0) + r0.y*__shfl(s, 1) + r0.z*__shfl(s, 2) + r0.w*__shfl(s, 3);
        acc += r1.x*__shfl(s, 4) + r1.y*__shfl(s, 5) + r1.z*__shfl(s, 6) + r1.w*__shfl(s, 7);
        acc += r2.x*__shfl(s, 8) + r2.y*__shfl(s, 9) + r2.z*__shfl(s,10) + r2.w*__shfl(s,11);
        acc += r3.x*__shfl(s,12) + r3.y*__shfl(s,13) + r3.z*__shfl(s,14) + r3.w*__shfl(s,15);
        acc += r4.x*__shfl(s,16) + r4.y*__shfl(s,17) + r4.z*__shfl(s,18) + r4.w*__shfl(s,19);
        acc += r5.x*__shfl(s,20) + r5.y*__shfl(s,21) + r5.z*__shfl(s,22) + r5.w*__shfl(s,23);
        acc += r6.x*__shfl(s,24) + r6.y*__shfl(s,25) + r6.z*__shfl(s,26) + r6.w*__shfl(s,27);
        acc += r7.x*__shfl(s,28) + r7.y*__shfl(s,29) + r7.z*__shfl(s,30) + r7.w*__shfl(s,31);
        s = acc;
    }
}

// ---------------------------------------------------------------------------
// Fallback: R9 kernel (proven, 73.4us) if ws_size is too small for the
// frame-parallel path. NBLK=4 cross-block write-once-slot protocol.
// ---------------------------------------------------------------------------
#define FB_NBLK  4
#define FB_CHUNK 16
#define FB_NCH   768
#define FB_NWAVE 12

#define FOREACH_S16(OP) \
    OP(s00) OP(s01) OP(s02) OP(s03) OP(s04) OP(s05) OP(s06) OP(s07) \
    OP(s08) OP(s09) OP(s10) OP(s11) OP(s12) OP(s13) OP(s14) OP(s15)

__global__ __launch_bounds__(FB_NCH, 3)
void biquad_fallback(const float* __restrict__ audio,
                     const float* __restrict__ params,
                     float* __restrict__ out,
                     unsigned int* __restrict__ ws)
{
    __shared__ float sc[NB][NF][16];
    __shared__ float sgain[2][NF];
    __shared__ float4 saggM[FB_NWAVE];
    __shared__ float  saggC[FB_NWAVE][2];
    __shared__ float  sv[FB_NWAVE][2];

    const int t       = threadIdx.x;
    const int xcd     = blockIdx.x & 7;
    const int slot_   = blockIdx.x >> 3;
    const int bt      = xcd * 4 + (slot_ & 3);
    const int quarter = slot_ >> 2;
    const int lane    = t & 63;
    const int wave    = t >> 6;
    const int frame   = quarter * 6 + (wave >> 1);

    if (t < NB * NF) {
        const int f  = t / NF;
        const int fr = t % NF;
        const float* P = params + (size_t)bt * 50 * NF;
        float tmp[13];
        filter_coeffs(f, P[(3*f+0)*NF+fr], P[(3*f+1)*NF+fr], P[(3*f+2)*NF+fr], tmp);
        // convert M8 -> M16 (one extra squaring) for CHUNK=16
        float u00 = tmp[9], u01 = tmp[10], u10 = tmp[11], u11 = tmp[12];
        const float n00 = u00*u00 + u01*u10;
        const float n01 = u00*u01 + u01*u11;
        const float n10 = u10*u00 + u11*u10;
        const float n11 = u10*u01 + u11*u11;
        sc[f][fr][0]=tmp[0]; sc[f][fr][1]=tmp[1]; sc[f][fr][2]=tmp[2]; sc[f][fr][3]=tmp[3];
        sc[f][fr][4]=tmp[4]; sc[f][fr][5]=tmp[5]; sc[f][fr][6]=tmp[6]; sc[f][fr][7]=tmp[7];
        sc[f][fr][8]=tmp[8]; sc[f][fr][9]=n00; sc[f][fr][10]=n01; sc[f][fr][11]=n10;
        sc[f][fr][12]=n11;
    }
    if (t >= 384 && t < 384 + 2 * NF) {
        const int idx = t - 384;
        const int which = idx / NF;
        const int fr    = idx % NF;
        const float* P = params + (size_t)bt * 50 * NF;
        const float p  = P[(48 + which) * NF + fr];
        sgain[which][fr] = __expf((-60.0f + 60.0f * p) * (2.30258509f / 20.0f));
    }
    __syncthreads();

    FOREACH_S16(DECL_S)
    {
        const float ing = sgain[0][frame];
        const float* base = audio + (size_t)bt * S + (size_t)(quarter * FB_NCH + t) * FB_CHUNK;
        float4 q;
        q = *(const float4*)(base +  0); s00 = q.x*ing; s01 = q.y*ing; s02 = q.z*ing; s03 = q.w*ing;
        q = *(const float4*)(base +  4); s04 = q.x*ing; s05 = q.y*ing; s06 = q.z*ing; s07 = q.w*ing;
        q = *(const float4*)(base +  8); s08 = q.x*ing; s09 = q.y*ing; s10 = q.z*ing; s11 = q.w*ing;
        q = *(const float4*)(base + 12); s12 = q.x*ing; s13 = q.y*ing; s14 = q.z*ing; s15 = q.w*ing;
    }

    #pragma unroll 1
    for (int f = 0; f < NB; f++) {
        const float4 q0 = *(const float4*)&sc[f][frame][0];
        const float4 q1 = *(const float4*)&sc[f][frame][4];
        const float4 q2 = *(const float4*)&sc[f][frame][8];
        const float  M11v = sc[f][frame][12];
        const float t00 = q0.x, t01 = q0.y, t10 = q0.z, t11 = q0.w;
        const float b0  = q1.x, b1  = q1.y, c0  = q1.z, c1  = q1.w;
        const float c2  = q2.x;

        float ic1 = 0.0f, ic2 = 0.0f;
        FOREACH_S16(STEPA)

        float Md00 = q2.y, Md01 = q2.z, Md10 = q2.w, Md11 = M11v;
        float Ac0 = ic1, Ac1 = ic2;
        #pragma unroll
        for (int d = 1; d < 64; d <<= 1) {
            const float lc0 = __shfl_up(Ac0, d);
            const float lc1 = __shfl_up(Ac1, d);
            if (lane >= d) {
                Ac0 = fmaf(Md00, lc0, fmaf(Md01, lc1, Ac0));
                Ac1 = fmaf(Md10, lc0, fmaf(Md11, lc1, Ac1));
            }
            const float n00 = Md00*Md00 + Md01*Md10;
            const float n01 = Md00*Md01 + Md01*Md11;
            const float n10 = Md10*Md00 + Md11*Md10;
            const float n11 = Md10*Md01 + Md11*Md11;
            Md00=n00; Md01=n01; Md10=n10; Md11=n11;
        }

        if (lane == 63) {
            saggM[wave] = make_float4(Md00, Md01, Md10, Md11);
            saggC[wave][0] = Ac0; saggC[wave][1] = Ac1;
        }
        __syncthreads();

        const unsigned int tag = (unsigned int)(f + 1);
        unsigned int* stagebase = ws + ((bt * NB + f) * FB_NBLK) * 8;

        if (wave == 0) {
            float G00 = 1.0f, G01 = 0.0f, G10 = 0.0f, G11 = 1.0f, Gc0 = 0.0f, Gc1 = 0.0f;
            if (lane < FB_NWAVE) {
                const float4 m = saggM[lane];
                G00 = m.x; G01 = m.y; G10 = m.z; G11 = m.w;
                Gc0 = saggC[lane][0]; Gc1 = saggC[lane][1];
            }
            #pragma unroll
            for (int d = 1; d < 16; d <<= 1) {
                const float l00 = __shfl_up(G00, d);
                const float l01 = __shfl_up(G01, d);
                const float l10 = __shfl_up(G10, d);
                const float l11 = __shfl_up(G11, d);
                const float lc0 = __shfl_up(Gc0, d);
                const float lc1 = __shfl_up(Gc1, d);
                if (lane >= d && lane < FB_NWAVE) {
                    const float n00 = G00*l00 + G01*l10;
                    const float n01 = G00*l01 + G01*l11;
                    const float n10 = G10*l00 + G11*l10;
                    const float n11 = G10*l01 + G11*l11;
                    const float nc0 = G00*lc0 + G01*lc1 + Gc0;
                    const float nc1 = G10*lc0 + G11*lc1 + Gc1;
                    G00=n00; G01=n01; G10=n10; G11=n11; Gc0=nc0; Gc1=nc1;
                }
            }

            if (quarter < FB_NBLK - 1 && lane == FB_NWAVE - 1) {
                unsigned int* slot = stagebase + quarter * 8;
                float* dp = (float*)(slot + 1);
                __hip_atomic_store(&dp[0], G00, __ATOMIC_RELAXED, __HIP_MEMORY_SCOPE_AGENT);
                __hip_atomic_store(&dp[1], G01, __ATOMIC_RELAXED, __HIP_MEMORY_SCOPE_AGENT);
                __hip_atomic_store(&dp[2], G10, __ATOMIC_RELAXED, __HIP_MEMORY_SCOPE_AGENT);
                __hip_atomic_store(&dp[3], G11, __ATOMIC_RELAXED, __HIP_MEMORY_SCOPE_AGENT);
                __hip_atomic_store(&dp[4], Gc0, __ATOMIC_RELAXED, __HIP_MEMORY_SCOPE_AGENT);
                __hip_atomic_store(&dp[5], Gc1, __ATOMIC_RELAXED, __HIP_MEMORY_SCOPE_AGENT);
                __hip_atomic_store(slot, tag, __ATOMIC_RELEASE, __HIP_MEMORY_SCOPE_AGENT);
            }

            float P00 = __shfl_up(G00, 1);
            float P01 = __shfl_up(G01, 1);
            float P10 = __shfl_up(G10, 1);
            float P11 = __shfl_up(G11, 1);
            float Pc0 = __shfl_up(Gc0, 1);
            float Pc1 = __shfl_up(Gc1, 1);
            if (lane == 0) { P00 = 1.0f; P01 = 0.0f; P10 = 0.0f; P11 = 1.0f; Pc0 = 0.0f; Pc1 = 0.0f; }

            float S0x = 0.0f, S0y = 0.0f;
            if (lane == 0 && quarter > 0) {
                float sx = 0.0f, sy = 0.0f;
                for (int k2 = 0; k2 < quarter; k2++) {
                    unsigned int* slot = stagebase + k2 * 8;
                    while (__hip_atomic_load(slot, __ATOMIC_ACQUIRE, __HIP_MEMORY_SCOPE_AGENT) != tag) {
                        __builtin_amdgcn_s_sleep(1);
                    }
                    float* dp = (float*)(slot + 1);
                    const float m00 = __hip_atomic_load(&dp[0], __ATOMIC_RELAXED, __HIP_MEMORY_SCOPE_AGENT);
                    const float m01 = __hip_atomic_load(&dp[1], __ATOMIC_RELAXED, __HIP_MEMORY_SCOPE_AGENT);
                    const float m10 = __hip_atomic_load(&dp[2], __ATOMIC_RELAXED, __HIP_MEMORY_SCOPE_AGENT);
                    const float m11 = __hip_atomic_load(&dp[3], __ATOMIC_RELAXED, __HIP_MEMORY_SCOPE_AGENT);
                    const float cc0 = __hip_atomic_load(&dp[4], __ATOMIC_RELAXED, __HIP_MEMORY_SCOPE_AGENT);
                    const float cc1 = __hip_atomic_load(&dp[5], __ATOMIC_RELAXED, __HIP_MEMORY_SCOPE_AGENT);
                    const float nx = m00 * sx + m01 * sy + cc0;
                    const float ny = m10 * sx + m11 * sy + cc1;
                    sx = nx; sy = ny;
                }
                S0x = sx; S0y = sy;
            }
            S0x = __shfl(S0x, 0);
            S0y = __shfl(S0y, 0);

            if (lane < FB_NWAVE) {
                sv[lane][0] = fmaf(P00, S0x, fmaf(P01, S0y, Pc0));
                sv[lane][1] = fmaf(P10, S0x, fmaf(P11, S0y, Pc1));
            }
        }
        __syncthreads();

        const float vx = sv[wave][0];
        const float vy = sv[wave][1];

        float ce0 = __shfl_up(Ac0, 1);
        float ce1 = __shfl_up(Ac1, 1);
        if (lane == 0) { ce0 = 0.0f; ce1 = 0.0f; }

        float w0 = vx, w1 = vy;
        float p00 = q2.y, p01 = q2.z, p10 = q2.w, p11 = M11v;
        #pragma unroll
        for (int b = 0; b < 6; b++) {
            if (lane & (1 << b)) {
                const float nw0 = fmaf(p00, w0, p01 * w1);
                const float nw1 = fmaf(p10, w0, p11 * w1);
                w0 = nw0; w1 = nw1;
            }
            if (b < 5) {
                const float n00 = p00*p00 + p01*p10;
                const float n01 = p00*p01 + p01*p11;
                const float n10 = p10*p00 + p11*p10;
                const float n11 = p10*p01 + p11*p11;
                p00=n00; p01=n01; p10=n10; p11=n11;
            }
        }
        ic1 = w0 + ce0;
        ic2 = w1 + ce1;

        FOREACH_S16(STEPC)
    }

    {
        const float og = sgain[1][frame];
        float* base = out + (size_t)bt * S + (size_t)(quarter * FB_NCH + t) * FB_CHUNK;
        float4 q;
        q.x = s00*og; q.y = s01*og; q.z = s02*og; q.w = s03*og; *(float4*)(base +  0) = q;
        q.x = s04*og; q.y = s05*og; q.z = s06*og; q.w = s07*og; *(float4*)(base +  4) = q;
        q.x = s08*og; q.y = s09*og; q.z = s10*og; q.w = s11*og; *(float4*)(base +  8) = q;
        q.x = s12*og; q.y = s13*og; q.z = s14*og; q.w = s15*og; *(float4*)(base + 12) = q;
    }
}

extern "C" void kernel_launch(void* const* d_in, const int* in_sizes, int n_in,
                              void* d_out, int out_size, void* d_ws, size_t ws_size,
                              hipStream_t stream)
{
    const float* audio  = (const float*)d_in[0];
    const float* params = (const float*)d_in[1];
    float* out = (float*)d_out;

    const size_t needed = ((size_t)WS_A_ELEMS + WS_B_ELEMS + WS_S_ELEMS) * sizeof(float);
    if (ws_size >= needed) {
        float* wsA = (float*)d_ws;
        float* wsB = wsA + WS_A_ELEMS;
        float* wsS = wsB + WS_B_ELEMS;
        frame_pass<<<NBATCH * NF, TPB, 0, stream>>>(audio, params, out, wsA, wsB, wsS, 0);
        relay_kernel<<<NBATCH, 64, 0, stream>>>(wsA, wsB, wsS);
        frame_pass<<<NBATCH * NF, TPB, 0, stream>>>(audio, params, out, wsA, wsB, wsS, 1);
    } else {
        biquad_fallback<<<FB_NBLK * NBATCH, FB_NCH, 0, stream>>>(
            audio, params, out, (unsigned int*)d_ws);
    }
}